// Round 10
// baseline (3166.413 us; speedup 1.0000x reference)
//
#include <hip/hip_runtime.h>
#include <hip/hip_bf16.h>

// LSTM: B=64, T=512, I=512, H=512. Output = final h [64,512] fp32.
//
// Round 10 = correctness recovery + single-variable isolation.
//   Rounds 8/9 failed (absmax ~0.09-0.11) with TWO unverified mechanisms
//   stacked: sc0-only XCD-L2 transport + XCC_ID purity consensus. The
//   8-cluster/8-batch LAYOUT has been re-derived repeatedly and is sound on
//   paper. This round keeps the layout UNCHANGED and reverts transport to
//   the round-6-PROVEN agent semantics: sc0 sc1 (MALL-served) on all h
//   publishes and polls. No purity machinery, no fences, no prep_flush
//   (kernel-boundary flushes cover prep->xgemm->rec visibility).
//   Pass => sc0/consensus transport was the bug. Fail => layout is the bug.
//
//   Carried (proven): xact = x@W_x via MFMA GEMM; tag-in-word h sync
//   (word = (step<<16)|bf16(h), double-buffered; poison tag 0xAAAA matches
//   no s<512; equal-tag stale replay lines carry bit-identical values);
//   dwordx4 batched polls + single vmcnt inside asm; s=0 poll skip (h0==0);
//   plain compiler-tracked xact prefetch one step ahead, after the poll;
//   gate-major B-tile (wave owns 4 hcols x 4 gates); XOR-butterfly gate
//   exchange; single barrier/step (double-buffered alds).
//   New micro-opt: MFMA in 4 independent chains (was 2) - halves the
//   dependent MFMA chain on the post-barrier critical path.

#define T_STEPS 512
#define NBATCH  64
#define HID     512
#define NCL     8
#define WPC     32
#define CLB     8

typedef __attribute__((ext_vector_type(8))) short bf16x8;
typedef __attribute__((ext_vector_type(4))) float f32x4;
typedef __attribute__((ext_vector_type(4))) unsigned u32x4;

// ws layout (bytes)
#define WS_WHF  0                        // whfrag bf16, frag-order: 2MB
#define WS_WXT  (4u<<20)                 // wxT bf16 [2048][512]: 2MB
#define WS_HB   (8u<<20)                 // hbuf tagged u32 [2][64][512]: 256KB
#define WS_XBF  (16u<<20)                // xbf bf16 [32768][512]: 32MB
#define WS_XACT (48u<<20)                // xact bf16 [512][64][2048]: 128MB
#define WS_NEED ((size_t)(48u<<20) + ((size_t)T_STEPS*NBATCH*2048*2))

__device__ __forceinline__ short f2bf(float f) {
    unsigned u = __float_as_uint(f);
    unsigned r = u + 0x7fffu + ((u >> 16) & 1u);   // RNE
    return (short)(r >> 16);
}

__global__ void prep_xbf(const float* __restrict__ x, short* __restrict__ xbf) {
    size_t i8 = ((size_t)blockIdx.x * 256 + threadIdx.x) * 8;   // 8192 blocks
    f32x4 lo = *(const f32x4*)(x + i8);
    f32x4 hi = *(const f32x4*)(x + i8 + 4);
    bf16x8 v;
    v[0]=f2bf(lo[0]); v[1]=f2bf(lo[1]); v[2]=f2bf(lo[2]); v[3]=f2bf(lo[3]);
    v[4]=f2bf(hi[0]); v[5]=f2bf(hi[1]); v[6]=f2bf(hi[2]); v[7]=f2bf(hi[3]);
    *(bf16x8*)(xbf + i8) = v;
}

// wxT[n][k] = W_g[k][h], n = g*512+h, k in [0,512)  (x-part rows of W)
__global__ void prep_wx(const float* __restrict__ Wf, const float* __restrict__ Wi,
                        const float* __restrict__ Wo, const float* __restrict__ Wc,
                        short* __restrict__ wxT) {
    int gid = blockIdx.x * 256 + threadIdx.x;      // 512 blocks
    int n = gid >> 6, k0 = (gid & 63) * 8;
    int g = n >> 9, h = n & 511;
    const float* Wg = (g == 0) ? Wf : (g == 1) ? Wi : (g == 2) ? Wo : Wc;
    bf16x8 v;
#pragma unroll
    for (int e = 0; e < 8; ++e) v[e] = f2bf(Wg[(k0 + e) * 512 + h]);
    *(bf16x8*)(wxT + (size_t)n * 512 + k0) = v;
}

// whfrag, frag-order, GATE-MAJOR cols: B-tile col (l&15) = gate*4+hcl,
// hcol = 16w + 4v + hcl; value = W_gate[512 + kk*32 + (l>>4)*8 + e][hcol]
__global__ void prep_wh(const float* __restrict__ Wf, const float* __restrict__ Wi,
                        const float* __restrict__ Wo, const float* __restrict__ Wc,
                        short* __restrict__ whfrag) {
    int gid = blockIdx.x * 256 + threadIdx.x;      // 512 blocks: 32w*4v*16kk*64l
    int l = gid & 63, kk = (gid >> 6) & 15, v = (gid >> 10) & 3, w = gid >> 12;
    int c16 = l & 15, gate = c16 >> 2, hcl = c16 & 3;
    int hcol = 16 * w + 4 * v + hcl;
    const float* Wg = (gate == 0) ? Wf : (gate == 1) ? Wi : (gate == 2) ? Wo : Wc;
    int krow = 512 + kk * 32 + (l >> 4) * 8;
    bf16x8 vv;
#pragma unroll
    for (int e = 0; e < 8; ++e) vv[e] = f2bf(Wg[(krow + e) * 512 + hcol]);
    *(bf16x8*)(whfrag + (size_t)gid * 8) = vv;
}

// xact GEMM: [M=32768,K=512] x [K=512,N=2048] -> xact[t][b][n] bf16
__launch_bounds__(256, 1)
__global__ void xgemm(const short* __restrict__ xbf, const short* __restrict__ wxT,
                      short* __restrict__ xact) {
    const int l  = threadIdx.x & 63;
    const int wv = threadIdx.x >> 6;
    const int m0 = blockIdx.y * 128 + (wv >> 1) * 64;
    const int n0 = blockIdx.x * 128 + (wv & 1) * 64;

    f32x4 acc[4][4] = {};
    const short* ap = xbf + (size_t)(m0 + (l & 15)) * 512 + (l >> 4) * 8;
    const short* bp = wxT + (size_t)(n0 + (l & 15)) * 512 + (l >> 4) * 8;

    for (int kk = 0; kk < 16; ++kk) {
        bf16x8 a[4], b[4];
#pragma unroll
        for (int r = 0; r < 4; ++r) a[r] = *(const bf16x8*)(ap + r * 8192 + kk * 32);
#pragma unroll
        for (int q = 0; q < 4; ++q) b[q] = *(const bf16x8*)(bp + q * 8192 + kk * 32);
#pragma unroll
        for (int r = 0; r < 4; ++r)
#pragma unroll
            for (int q = 0; q < 4; ++q)
                acc[r][q] = __builtin_amdgcn_mfma_f32_16x16x32_bf16(a[r], b[q], acc[r][q], 0, 0, 0);
    }
#pragma unroll
    for (int r = 0; r < 4; ++r)
#pragma unroll
        for (int q = 0; q < 4; ++q)
#pragma unroll
            for (int j = 0; j < 4; ++j) {
                int m = m0 + r * 16 + (l >> 4) * 4 + j;
                int b_ = m >> 9, t = m & 511;
                int n = n0 + q * 16 + (l & 15);
                xact[((size_t)t * 64 + b_) * 2048 + n] = f2bf(acc[r][q][j]);
            }
}

__device__ __forceinline__ f32x4 shfx4(f32x4 v, int mask) {
    f32x4 r;
#pragma unroll
    for (int e = 0; e < 4; ++e) r[e] = __shfl_xor(v[e], mask, 64);
    return r;
}
__device__ __forceinline__ u32x4 pack8(u32x4 a, u32x4 b) {
    u32x4 r;
    r[0] = __builtin_amdgcn_perm(a[1], a[0], 0x05040100u);
    r[1] = __builtin_amdgcn_perm(a[3], a[2], 0x05040100u);
    r[2] = __builtin_amdgcn_perm(b[1], b[0], 0x05040100u);
    r[3] = __builtin_amdgcn_perm(b[3], b[2], 0x05040100u);
    return r;
}

// 8 x 16B tagged poll loads, agent-coherent (MALL), one vmcnt inside the block
#define POLL8                                                                 \
    asm volatile(                                                             \
        "global_load_dwordx4 %[t0], %[p], off sc0 sc1\n\t"                    \
        "global_load_dwordx4 %[t1], %[p], off offset:16 sc0 sc1\n\t"          \
        "global_load_dwordx4 %[t2], %[p], off offset:128 sc0 sc1\n\t"         \
        "global_load_dwordx4 %[t3], %[p], off offset:144 sc0 sc1\n\t"         \
        "global_load_dwordx4 %[t4], %[p], off offset:256 sc0 sc1\n\t"         \
        "global_load_dwordx4 %[t5], %[p], off offset:272 sc0 sc1\n\t"         \
        "global_load_dwordx4 %[t6], %[p], off offset:384 sc0 sc1\n\t"         \
        "global_load_dwordx4 %[t7], %[p], off offset:400 sc0 sc1\n\t"         \
        "s_waitcnt vmcnt(0)"                                                  \
        : [t0]"=v"(t0), [t1]"=v"(t1), [t2]"=v"(t2), [t3]"=v"(t3),             \
          [t4]"=v"(t4), [t5]"=v"(t5), [t6]"=v"(t6), [t7]"=v"(t7)              \
        : [p]"v"(hp) : "memory")

// ---- recurrence -------------------------------------------------------------
__launch_bounds__(256, 1)
__global__ void lstm_rec(const short* __restrict__ xact,
                         const float* __restrict__ bfp, const float* __restrict__ bip,
                         const float* __restrict__ bop, const float* __restrict__ bcp,
                         const short* __restrict__ whfrag,
                         unsigned* __restrict__ hbuf,     // [2][64][512] tagged
                         float* __restrict__ out)         // [64][512] fp32
{
    const int tid = threadIdx.x;
    const int v   = tid >> 6;           // wave = hcol sub-slice
    const int l   = tid & 63;
    const int bid = blockIdx.x;
    const int cl  = bid & (NCL - 1);    // cluster (8 batches)
    const int w   = bid >> 3;           // 0..31: 16 hcols of 512
    const int batch0 = cl * CLB;

    // ---- W_h fragments: 16 x bf16x8, register-resident ----
    bf16x8 wfr[16];
    {
        const short* wp = whfrag + (((size_t)(w * 4 + v) * 16) * 64 + l) * 8;
#pragma unroll
        for (int kk = 0; kk < 16; ++kk)
            wfr[kk] = *(const bf16x8*)(wp + (size_t)kk * 512);
#pragma unroll
        for (int kk = 0; kk < 16; ++kk)
            asm volatile("" : "+v"(wfr[kk]));
    }

    const int g    = (l >> 2) & 3;              // lane's gate
    const int hcol = 16 * w + 4 * v + (l & 3);  // lane's h column
    const int kg   = l >> 4;
    const float* bp2 = (g == 0) ? bfp : (g == 1) ? bip : (g == 2) ? bop : bcp;
    const float bias = bp2[hcol];
    // unified activation: act = A*rcp(1+exp2(K*x)) + C
    const float Aa = (g == 3) ? 2.f : 1.f;
    const float Kk = (g == 3) ? -2.885390082f : -1.442695041f;
    const float Cc = (g == 3) ? -1.f : 0.f;

    __shared__ short alds[2][16][64][8];   // A-frags, double-buffered (32KB)

    const int rphys  = batch0 + (l & 7);    // poll row (A rows 8..15 dup 0..7)
    const int rowoff = 4 * kg + g;          // D-row offset this lane owns
    const unsigned short* xa = (const unsigned short*)xact;
    size_t xoff[4];                         // xact offsets (rows clamped to 8)
#pragma unroll
    for (int j = 0; j < 4; ++j)
        xoff[j] = ((size_t)(batch0 + ((4 * kg + j) & 7))) * 2048 + (size_t)g * 512 + hcol;

    f32x4 c = {0.f, 0.f, 0.f, 0.f};
    bool dead = false;

    // xact for s=0: plain compiler-tracked loads
    unsigned short xw[4], xwn[4];
#pragma unroll
    for (int j = 0; j < 4; ++j) xw[j] = xa[xoff[j]];

    for (int s = 0; s < T_STEPS; ++s) {
        // ---- poll K-quarter v of h_s (tag-in-word; skip at s=0: h0=0) ----
        u32x4 t0 = {}, t1 = {}, t2 = {}, t3 = {}, t4 = {}, t5 = {}, t6 = {}, t7 = {};
        if (s) {
            const char* hp = (const char*)(hbuf + (s & 1) * (NBATCH * HID)
                                           + rphys * HID + v * 128 + kg * 8);
            const unsigned tagw = (unsigned)s << 16;
            int spin = 0;
            while (true) {
                POLL8;
                unsigned m = 0;
#pragma unroll
                for (int e = 0; e < 4; ++e) {
                    m |= (t0[e] ^ tagw) & 0xFFFF0000u; m |= (t1[e] ^ tagw) & 0xFFFF0000u;
                    m |= (t2[e] ^ tagw) & 0xFFFF0000u; m |= (t3[e] ^ tagw) & 0xFFFF0000u;
                    m |= (t4[e] ^ tagw) & 0xFFFF0000u; m |= (t5[e] ^ tagw) & 0xFFFF0000u;
                    m |= (t6[e] ^ tagw) & 0xFFFF0000u; m |= (t7[e] ^ tagw) & 0xFFFF0000u;
                }
                if (__all(m == 0) || dead) break;
                if (++spin > (1 << 17)) dead = true;
                else if (spin > 16) __builtin_amdgcn_s_sleep(1);
            }
        }

        // ---- xact prefetch for s+1 (plain loads, compiler-tracked) ----
        if (s + 1 < T_STEPS) {
#pragma unroll
            for (int j = 0; j < 4; ++j)
                xwn[j] = xa[(size_t)(s + 1) * 131072 + xoff[j]];
        }

        // ---- ds_write own 4 frags (tag-strip via v_perm) ----
        const int par = s & 1;
        *(u32x4*)&alds[par][v * 4 + 0][l][0] = pack8(t0, t1);
        *(u32x4*)&alds[par][v * 4 + 1][l][0] = pack8(t2, t3);
        *(u32x4*)&alds[par][v * 4 + 2][l][0] = pack8(t4, t5);
        *(u32x4*)&alds[par][v * 4 + 3][l][0] = pack8(t6, t7);
        __syncthreads();   // single barrier per step (dbuf makes it safe)

        // ---- 16 MFMA over K=512, 4 independent chains ----
        f32x4 acc0 = {0.f,0.f,0.f,0.f}, acc1 = {0.f,0.f,0.f,0.f};
        f32x4 acc2 = {0.f,0.f,0.f,0.f}, acc3 = {0.f,0.f,0.f,0.f};
#pragma unroll
        for (int kk = 0; kk < 16; kk += 4) {
            bf16x8 a0 = *(const bf16x8*)&alds[par][kk][l][0];
            bf16x8 a1 = *(const bf16x8*)&alds[par][kk + 1][l][0];
            bf16x8 a2 = *(const bf16x8*)&alds[par][kk + 2][l][0];
            bf16x8 a3 = *(const bf16x8*)&alds[par][kk + 3][l][0];
            acc0 = __builtin_amdgcn_mfma_f32_16x16x32_bf16(a0, wfr[kk],     acc0, 0, 0, 0);
            acc1 = __builtin_amdgcn_mfma_f32_16x16x32_bf16(a1, wfr[kk + 1], acc1, 0, 0, 0);
            acc2 = __builtin_amdgcn_mfma_f32_16x16x32_bf16(a2, wfr[kk + 2], acc2, 0, 0, 0);
            acc3 = __builtin_amdgcn_mfma_f32_16x16x32_bf16(a3, wfr[kk + 3], acc3, 0, 0, 0);
        }
        f32x4 pre = (acc0 + acc1) + (acc2 + acc3);

        // ---- unified activation: act = A*rcp(1+exp2(K*x)) + C ----
        f32x4 own;
#pragma unroll
        for (int j = 0; j < 4; ++j) {
            float vv = pre[j] + __uint_as_float((unsigned)xw[j] << 16) + bias;
            float e  = __builtin_amdgcn_exp2f(Kk * vv);
            own[j]   = __builtin_fmaf(Aa, __builtin_amdgcn_rcpf(1.f + e), Cc);
        }
#pragma unroll
        for (int j = 0; j < 4; ++j) xw[j] = xwn[j];

        // ---- XOR butterfly: gather f,i,o,C across lanes l^4, l^8 ----
        f32x4 r1 = shfx4(own, 4);
        f32x4 r2 = shfx4(own, 8);
        f32x4 r3 = shfx4(r1, 8);
        f32x4 fv = (g == 0) ? own : (g == 1) ? r1 : (g == 2) ? r2 : r3;
        f32x4 iv = (g == 0) ? r1 : (g == 1) ? own : (g == 2) ? r3 : r2;
        f32x4 ov = (g == 0) ? r2 : (g == 1) ? r3 : (g == 2) ? own : r1;
        f32x4 Cv = (g == 0) ? r3 : (g == 1) ? r2 : (g == 2) ? r1 : own;

        c = fv * c + iv * Cv;   // 4x lane-redundant, deterministic

        // ---- publish row rowoff (this lane's gate) ----
        float cg = (g == 0) ? c[0] : (g == 1) ? c[1] : (g == 2) ? c[2] : c[3];
        float og = (g == 0) ? ov[0] : (g == 1) ? ov[1] : (g == 2) ? ov[2] : ov[3];
        float e2 = __builtin_amdgcn_exp2f(-2.885390082f * cg);
        float th = __builtin_fmaf(2.f, __builtin_amdgcn_rcpf(1.f + e2), -1.f);
        float h  = og * th;
        if (rowoff < CLB) {
            const int row = batch0 + rowoff;
            if (s == T_STEPS - 1) {
                out[row * HID + hcol] = h;
            } else {
                unsigned* hd = hbuf + ((s + 1) & 1) * (NBATCH * HID) + row * HID + hcol;
                unsigned  hv = ((unsigned)(s + 1) << 16) |
                               (unsigned)(unsigned short)f2bf(h);
                asm volatile("global_store_dword %0, %1, off sc0 sc1"
                             :: "v"(hd), "v"(hv) : "memory");
            }
        }
    }
}

extern "C" void kernel_launch(void* const* d_in, const int* in_sizes, int n_in,
                              void* d_out, int out_size, void* d_ws, size_t ws_size,
                              hipStream_t stream) {
    const float* x  = (const float*)d_in[0];
    const float* Wf = (const float*)d_in[1];
    const float* bf = (const float*)d_in[2];
    const float* Wi = (const float*)d_in[3];
    const float* bi = (const float*)d_in[4];
    const float* Wo = (const float*)d_in[5];
    const float* bo = (const float*)d_in[6];
    const float* Wc = (const float*)d_in[7];
    const float* bc = (const float*)d_in[8];

    if (ws_size < WS_NEED) return;   // loud failure: out stays poison

    char*     ws     = (char*)d_ws;
    short*    whfrag = (short*)(ws + WS_WHF);
    short*    wxT    = (short*)(ws + WS_WXT);
    unsigned* hbuf   = (unsigned*)(ws + WS_HB);
    short*    xbf    = (short*)(ws + WS_XBF);
    short*    xact   = (short*)(ws + WS_XACT);

    prep_xbf <<<dim3(8192), dim3(256), 0, stream>>>(x, xbf);
    prep_wx  <<<dim3(512),  dim3(256), 0, stream>>>(Wf, Wi, Wo, Wc, wxT);
    prep_wh  <<<dim3(512),  dim3(256), 0, stream>>>(Wf, Wi, Wo, Wc, whfrag);
    xgemm    <<<dim3(16, 256), dim3(256), 0, stream>>>(xbf, wxT, xact);
    lstm_rec <<<dim3(NCL * WPC), dim3(256), 0, stream>>>(
        xact, bf, bi, bo, bc, whfrag, hbuf, (float*)d_out);
}

// Round 11
// 1752.648 us; speedup vs baseline: 1.8066x; 1.8066x over previous
//
#include <hip/hip_runtime.h>
#include <hip/hip_bf16.h>

// LSTM: B=64, T=512, I=512, H=512. Output = final h [64,512] fp32.
//
// Round 11 = wave-contiguous h transport + back to 4 clusters.
//   Round 10 evidence: 256 pollers (8 clusters) > 128 (4 clusters) made
//   steps SLOWER (5.7 vs 4.3us) -> MALL congestion from poll traffic; and
//   WRITE_SIZE 131MB for 64MB of h -> scattered 4B stores pay ~2x
//   partial-line amplification (fetch side pays the same on polls).
//   Fix: h transport layout = slot per producer wave:
//     hbuf[parity][cl][(w*4+v)*64 + lane]  (tag<<16 | bf16(h) per word)
//   Producer wave publish = 256B contiguous (4 full lines, was 64 partial).
//   Consumer wave v's K-quarter = contiguous slots [32v,32v+32) = 8KB;
//   polled as 8 x dwordx4 at lane*16 + m*1024 -> every instruction is a
//   fully-coalesced 1KB stream. Tag-in-word preserved (every consumed word
//   tag-checked; poll IS the payload; 1 trip/step).
//   Slot->A-frag permutation (verified bijective): chunk m of lane l holds
//   producer (w'=8v+m, v'=l>>4, rows via group=l&15):
//     kk = 4v + (m>>1), kgrp Q = (2m + (l>>5))&3, row = l&15,
//     e0 = 4*((l>>4)&1); 4 tagged words -> 2 dwords -> ds_write_b64.
//   Carried: 4 clusters x 32 WGs x 16 batches (128 WGs, proven fastest);
//   agent (sc0 sc1) transport (round-10-proven; sc0-only was rounds-8/9's
//   bug); s=0 poll skip (h0==0, zero frags); 4-chain MFMA; xact = x@W_x
//   precomputed; gate-major B-tile + XOR-butterfly; W_h register-resident;
//   single barrier/step with double-buffered alds.

#define T_STEPS 512
#define NBATCH  64
#define HID     512
#define NCL     4
#define WPC     32
#define CLB     16

typedef __attribute__((ext_vector_type(8))) short bf16x8;
typedef __attribute__((ext_vector_type(4))) float f32x4;
typedef __attribute__((ext_vector_type(4))) unsigned u32x4;
typedef __attribute__((ext_vector_type(2))) unsigned u32x2;

// ws layout (bytes)
#define WS_WHF  0                        // whfrag bf16, frag-order: 2MB
#define WS_WXT  (4u<<20)                 // wxT bf16 [2048][512]: 2MB
#define WS_HB   (8u<<20)                 // hbuf tagged u32 [2][4][8192]: 256KB
#define WS_XBF  (16u<<20)                // xbf bf16 [32768][512]: 32MB
#define WS_XACT (48u<<20)                // xact bf16 [512][64][2048]: 128MB
#define WS_NEED ((size_t)(48u<<20) + ((size_t)T_STEPS*NBATCH*2048*2))

__device__ __forceinline__ short f2bf(float f) {
    unsigned u = __float_as_uint(f);
    unsigned r = u + 0x7fffu + ((u >> 16) & 1u);   // RNE
    return (short)(r >> 16);
}

__global__ void prep_xbf(const float* __restrict__ x, short* __restrict__ xbf) {
    size_t i8 = ((size_t)blockIdx.x * 256 + threadIdx.x) * 8;   // 8192 blocks
    f32x4 lo = *(const f32x4*)(x + i8);
    f32x4 hi = *(const f32x4*)(x + i8 + 4);
    bf16x8 v;
    v[0]=f2bf(lo[0]); v[1]=f2bf(lo[1]); v[2]=f2bf(lo[2]); v[3]=f2bf(lo[3]);
    v[4]=f2bf(hi[0]); v[5]=f2bf(hi[1]); v[6]=f2bf(hi[2]); v[7]=f2bf(hi[3]);
    *(bf16x8*)(xbf + i8) = v;
}

// wxT[n][k] = W_g[k][h], n = g*512+h, k in [0,512)  (x-part rows of W)
__global__ void prep_wx(const float* __restrict__ Wf, const float* __restrict__ Wi,
                        const float* __restrict__ Wo, const float* __restrict__ Wc,
                        short* __restrict__ wxT) {
    int gid = blockIdx.x * 256 + threadIdx.x;      // 512 blocks
    int n = gid >> 6, k0 = (gid & 63) * 8;
    int g = n >> 9, h = n & 511;
    const float* Wg = (g == 0) ? Wf : (g == 1) ? Wi : (g == 2) ? Wo : Wc;
    bf16x8 v;
#pragma unroll
    for (int e = 0; e < 8; ++e) v[e] = f2bf(Wg[(k0 + e) * 512 + h]);
    *(bf16x8*)(wxT + (size_t)n * 512 + k0) = v;
}

// whfrag, frag-order, GATE-MAJOR cols: B-tile col (l&15) = gate*4+hcl,
// hcol = 16w + 4v + hcl; value = W_gate[512 + kk*32 + (l>>4)*8 + e][hcol]
__global__ void prep_wh(const float* __restrict__ Wf, const float* __restrict__ Wi,
                        const float* __restrict__ Wo, const float* __restrict__ Wc,
                        short* __restrict__ whfrag) {
    int gid = blockIdx.x * 256 + threadIdx.x;      // 512 blocks: 32w*4v*16kk*64l
    int l = gid & 63, kk = (gid >> 6) & 15, v = (gid >> 10) & 3, w = gid >> 12;
    int c16 = l & 15, gate = c16 >> 2, hcl = c16 & 3;
    int hcol = 16 * w + 4 * v + hcl;
    const float* Wg = (gate == 0) ? Wf : (gate == 1) ? Wi : (gate == 2) ? Wo : Wc;
    int krow = 512 + kk * 32 + (l >> 4) * 8;
    bf16x8 vv;
#pragma unroll
    for (int e = 0; e < 8; ++e) vv[e] = f2bf(Wg[(krow + e) * 512 + hcol]);
    *(bf16x8*)(whfrag + (size_t)gid * 8) = vv;
}

// xact GEMM: [M=32768,K=512] x [K=512,N=2048] -> xact[t][b][n] bf16
__launch_bounds__(256, 1)
__global__ void xgemm(const short* __restrict__ xbf, const short* __restrict__ wxT,
                      short* __restrict__ xact) {
    const int l  = threadIdx.x & 63;
    const int wv = threadIdx.x >> 6;
    const int m0 = blockIdx.y * 128 + (wv >> 1) * 64;
    const int n0 = blockIdx.x * 128 + (wv & 1) * 64;

    f32x4 acc[4][4] = {};
    const short* ap = xbf + (size_t)(m0 + (l & 15)) * 512 + (l >> 4) * 8;
    const short* bp = wxT + (size_t)(n0 + (l & 15)) * 512 + (l >> 4) * 8;

    for (int kk = 0; kk < 16; ++kk) {
        bf16x8 a[4], b[4];
#pragma unroll
        for (int r = 0; r < 4; ++r) a[r] = *(const bf16x8*)(ap + r * 8192 + kk * 32);
#pragma unroll
        for (int q = 0; q < 4; ++q) b[q] = *(const bf16x8*)(bp + q * 8192 + kk * 32);
#pragma unroll
        for (int r = 0; r < 4; ++r)
#pragma unroll
            for (int q = 0; q < 4; ++q)
                acc[r][q] = __builtin_amdgcn_mfma_f32_16x16x32_bf16(a[r], b[q], acc[r][q], 0, 0, 0);
    }
#pragma unroll
    for (int r = 0; r < 4; ++r)
#pragma unroll
        for (int q = 0; q < 4; ++q)
#pragma unroll
            for (int j = 0; j < 4; ++j) {
                int m = m0 + r * 16 + (l >> 4) * 4 + j;
                int b_ = m >> 9, t = m & 511;
                int n = n0 + q * 16 + (l & 15);
                xact[((size_t)t * 64 + b_) * 2048 + n] = f2bf(acc[r][q][j]);
            }
}

__device__ __forceinline__ f32x4 shfx4(f32x4 v, int mask) {
    f32x4 r;
#pragma unroll
    for (int e = 0; e < 4; ++e) r[e] = __shfl_xor(v[e], mask, 64);
    return r;
}

// 8 x 16B coalesced poll loads (two bases: 13-bit signed offset caps at 4095)
#define POLL8X                                                                \
    asm volatile(                                                             \
        "global_load_dwordx4 %[t0], %[p], off sc0 sc1\n\t"                    \
        "global_load_dwordx4 %[t1], %[p], off offset:1024 sc0 sc1\n\t"        \
        "global_load_dwordx4 %[t2], %[p], off offset:2048 sc0 sc1\n\t"        \
        "global_load_dwordx4 %[t3], %[p], off offset:3072 sc0 sc1\n\t"        \
        "global_load_dwordx4 %[t4], %[q], off sc0 sc1\n\t"                    \
        "global_load_dwordx4 %[t5], %[q], off offset:1024 sc0 sc1\n\t"        \
        "global_load_dwordx4 %[t6], %[q], off offset:2048 sc0 sc1\n\t"        \
        "global_load_dwordx4 %[t7], %[q], off offset:3072 sc0 sc1\n\t"        \
        "s_waitcnt vmcnt(0)"                                                  \
        : [t0]"=v"(t0), [t1]"=v"(t1), [t2]"=v"(t2), [t3]"=v"(t3),             \
          [t4]"=v"(t4), [t5]"=v"(t5), [t6]"=v"(t6), [t7]"=v"(t7)              \
        : [p]"v"(hp), [q]"v"(hq) : "memory")

// ---- recurrence -------------------------------------------------------------
__launch_bounds__(256, 1)
__global__ void lstm_rec(const short* __restrict__ xact,
                         const float* __restrict__ bfp, const float* __restrict__ bip,
                         const float* __restrict__ bop, const float* __restrict__ bcp,
                         const short* __restrict__ whfrag,
                         unsigned* __restrict__ hbuf,     // [2][4][8192] tagged
                         float* __restrict__ out)         // [64][512] fp32
{
    const int tid = threadIdx.x;
    const int v   = tid >> 6;           // wave = hcol sub-slice / K-quarter
    const int l   = tid & 63;
    const int bid = blockIdx.x;
    const int cl  = bid & (NCL - 1);    // cluster (16 batches)
    const int w   = bid >> 2;           // 0..31: 16 hcols of 512
    const int batch0 = cl * CLB;

    // ---- W_h fragments: 16 x bf16x8, register-resident ----
    bf16x8 wfr[16];
    {
        const short* wp = whfrag + (((size_t)(w * 4 + v) * 16) * 64 + l) * 8;
#pragma unroll
        for (int kk = 0; kk < 16; ++kk)
            wfr[kk] = *(const bf16x8*)(wp + (size_t)kk * 512);
#pragma unroll
        for (int kk = 0; kk < 16; ++kk)
            asm volatile("" : "+v"(wfr[kk]));
    }

    const int g    = (l >> 2) & 3;              // lane's gate
    const int hcol = 16 * w + 4 * v + (l & 3);  // lane's h column
    const int kg   = l >> 4;
    const float* bp2 = (g == 0) ? bfp : (g == 1) ? bip : (g == 2) ? bop : bcp;
    const float bias = bp2[hcol];
    // unified activation: act = A*rcp(1+exp2(K*x)) + C
    const float Aa = (g == 3) ? 2.f : 1.f;
    const float Kk = (g == 3) ? -2.885390082f : -1.442695041f;
    const float Cc = (g == 3) ? -1.f : 0.f;

    __shared__ short alds[2][16][64][8];   // A-frags, double-buffered (32KB)

    const int rowD0 = batch0 + kg * 4;      // D-frag row base (+j)
    const unsigned short* xa = (const unsigned short*)xact;
    size_t xoff[4];
#pragma unroll
    for (int j = 0; j < 4; ++j)
        xoff[j] = (size_t)(rowD0 + j) * 2048 + (size_t)g * 512 + hcol;

    // slot permutation constants (derived & verified in round-11 notes):
    // chunk m of lane l = producer (w'=8v+m, v'=l>>4, group=l&15):
    //   kk = 4v+(m>>1), Q = (2m+(l>>5))&3, row = l&15, e0 = 4*((l>>4)&1)
    const int rowT = l & 15;
    const int qb   = l >> 5;          // Q bias
    const int e0s  = 4 * ((l >> 4) & 1);

    f32x4 c = {0.f, 0.f, 0.f, 0.f};
    bool dead = false;

    // xact for s=0 (plain compiler-tracked loads)
    unsigned short xw[4], xwn[4];
#pragma unroll
    for (int j = 0; j < 4; ++j) xw[j] = xa[xoff[j]];

    for (int s = 0; s < T_STEPS; ++s) {
        // ---- poll K-quarter v of h_s: 8KB slot region, fully coalesced ----
        u32x4 t0 = {}, t1 = {}, t2 = {}, t3 = {}, t4 = {}, t5 = {}, t6 = {}, t7 = {};
        if (s) {
            const char* hp = (const char*)(hbuf + (size_t)(s & 1) * (NCL * 8192)
                                           + cl * 8192 + v * 2048) + l * 16;
            const char* hq = hp + 4096;
            const unsigned tagw = (unsigned)s << 16;
            int spin = 0;
            while (true) {
                POLL8X;
                unsigned m = 0;
#pragma unroll
                for (int e = 0; e < 4; ++e) {
                    m |= (t0[e] ^ tagw) & 0xFFFF0000u; m |= (t1[e] ^ tagw) & 0xFFFF0000u;
                    m |= (t2[e] ^ tagw) & 0xFFFF0000u; m |= (t3[e] ^ tagw) & 0xFFFF0000u;
                    m |= (t4[e] ^ tagw) & 0xFFFF0000u; m |= (t5[e] ^ tagw) & 0xFFFF0000u;
                    m |= (t6[e] ^ tagw) & 0xFFFF0000u; m |= (t7[e] ^ tagw) & 0xFFFF0000u;
                }
                if (__all(m == 0) || dead) break;
                if (++spin > (1 << 17)) dead = true;
                else if (spin > 16) __builtin_amdgcn_s_sleep(1);
            }
        }

        // ---- xact prefetch for s+1 (plain loads, compiler-tracked) ----
        if (s + 1 < T_STEPS) {
#pragma unroll
            for (int j = 0; j < 4; ++j)
                xwn[j] = xa[(size_t)(s + 1) * 131072 + xoff[j]];
        }

        // ---- slot->A-frag permutation: tag-strip + 8 x ds_write_b64 ----
        const int par = s & 1;
#define WRCHUNK(mm, tv)                                                        \
        {                                                                      \
            u32x2 d;                                                           \
            d[0] = __builtin_amdgcn_perm(tv[1], tv[0], 0x05040100u);           \
            d[1] = __builtin_amdgcn_perm(tv[3], tv[2], 0x05040100u);           \
            const int Qw = (2 * (mm) + qb) & 3;                                \
            *(u32x2*)&alds[par][4 * v + ((mm) >> 1)][(Qw << 4) | rowT][e0s] = d; \
        }
        WRCHUNK(0, t0) WRCHUNK(1, t1) WRCHUNK(2, t2) WRCHUNK(3, t3)
        WRCHUNK(4, t4) WRCHUNK(5, t5) WRCHUNK(6, t6) WRCHUNK(7, t7)
#undef WRCHUNK
        __syncthreads();   // single barrier per step (dbuf makes it safe)

        // ---- 16 MFMA over K=512, 4 independent chains ----
        f32x4 acc0 = {0.f,0.f,0.f,0.f}, acc1 = {0.f,0.f,0.f,0.f};
        f32x4 acc2 = {0.f,0.f,0.f,0.f}, acc3 = {0.f,0.f,0.f,0.f};
#pragma unroll
        for (int kk = 0; kk < 16; kk += 4) {
            bf16x8 a0 = *(const bf16x8*)&alds[par][kk][l][0];
            bf16x8 a1 = *(const bf16x8*)&alds[par][kk + 1][l][0];
            bf16x8 a2 = *(const bf16x8*)&alds[par][kk + 2][l][0];
            bf16x8 a3 = *(const bf16x8*)&alds[par][kk + 3][l][0];
            acc0 = __builtin_amdgcn_mfma_f32_16x16x32_bf16(a0, wfr[kk],     acc0, 0, 0, 0);
            acc1 = __builtin_amdgcn_mfma_f32_16x16x32_bf16(a1, wfr[kk + 1], acc1, 0, 0, 0);
            acc2 = __builtin_amdgcn_mfma_f32_16x16x32_bf16(a2, wfr[kk + 2], acc2, 0, 0, 0);
            acc3 = __builtin_amdgcn_mfma_f32_16x16x32_bf16(a3, wfr[kk + 3], acc3, 0, 0, 0);
        }
        f32x4 pre = (acc0 + acc1) + (acc2 + acc3);

        // ---- unified activation: act = A*rcp(1+exp2(K*x)) + C ----
        f32x4 own;
#pragma unroll
        for (int j = 0; j < 4; ++j) {
            float vv = pre[j] + __uint_as_float((unsigned)xw[j] << 16) + bias;
            float e  = __builtin_amdgcn_exp2f(Kk * vv);
            own[j]   = __builtin_fmaf(Aa, __builtin_amdgcn_rcpf(1.f + e), Cc);
        }
#pragma unroll
        for (int j = 0; j < 4; ++j) xw[j] = xwn[j];

        // ---- XOR butterfly: gather f,i,o,C across lanes l^4, l^8 ----
        f32x4 r1 = shfx4(own, 4);
        f32x4 r2 = shfx4(own, 8);
        f32x4 r3 = shfx4(r1, 8);
        f32x4 fv = (g == 0) ? own : (g == 1) ? r1 : (g == 2) ? r2 : r3;
        f32x4 iv = (g == 0) ? r1 : (g == 1) ? own : (g == 2) ? r3 : r2;
        f32x4 ov = (g == 0) ? r2 : (g == 1) ? r3 : (g == 2) ? own : r1;
        f32x4 Cv = (g == 0) ? r3 : (g == 1) ? r2 : (g == 2) ? r1 : own;

        c = fv * c + iv * Cv;   // 4x lane-redundant, deterministic

        // ---- publish: wave-contiguous slot store (4 full lines/wave) ----
        float cg = (g == 0) ? c[0] : (g == 1) ? c[1] : (g == 2) ? c[2] : c[3];
        float og = (g == 0) ? ov[0] : (g == 1) ? ov[1] : (g == 2) ? ov[2] : ov[3];
        float e2 = __builtin_amdgcn_exp2f(-2.885390082f * cg);
        float th = __builtin_fmaf(2.f, __builtin_amdgcn_rcpf(1.f + e2), -1.f);
        float h  = og * th;
        if (s == T_STEPS - 1) {
            out[(rowD0 + g) * HID + hcol] = h;
        } else {
            unsigned* hd = hbuf + (size_t)((s + 1) & 1) * (NCL * 8192)
                         + cl * 8192 + (w * 4 + v) * 64 + l;
            unsigned  hv = ((unsigned)(s + 1) << 16) |
                           (unsigned)(unsigned short)f2bf(h);
            asm volatile("global_store_dword %0, %1, off sc0 sc1"
                         :: "v"(hd), "v"(hv) : "memory");
        }
    }
}

extern "C" void kernel_launch(void* const* d_in, const int* in_sizes, int n_in,
                              void* d_out, int out_size, void* d_ws, size_t ws_size,
                              hipStream_t stream) {
    const float* x  = (const float*)d_in[0];
    const float* Wf = (const float*)d_in[1];
    const float* bf = (const float*)d_in[2];
    const float* Wi = (const float*)d_in[3];
    const float* bi = (const float*)d_in[4];
    const float* Wo = (const float*)d_in[5];
    const float* bo = (const float*)d_in[6];
    const float* Wc = (const float*)d_in[7];
    const float* bc = (const float*)d_in[8];

    if (ws_size < WS_NEED) return;   // loud failure: out stays poison

    char*     ws     = (char*)d_ws;
    short*    whfrag = (short*)(ws + WS_WHF);
    short*    wxT    = (short*)(ws + WS_WXT);
    unsigned* hbuf   = (unsigned*)(ws + WS_HB);
    short*    xbf    = (short*)(ws + WS_XBF);
    short*    xact   = (short*)(ws + WS_XACT);

    prep_xbf <<<dim3(8192), dim3(256), 0, stream>>>(x, xbf);
    prep_wx  <<<dim3(512),  dim3(256), 0, stream>>>(Wf, Wi, Wo, Wc, wxT);
    prep_wh  <<<dim3(512),  dim3(256), 0, stream>>>(Wf, Wi, Wo, Wc, whfrag);
    xgemm    <<<dim3(16, 256), dim3(256), 0, stream>>>(xbf, wxT, xact);
    lstm_rec <<<dim3(NCL * WPC), dim3(256), 0, stream>>>(
        xact, bf, bi, bo, bc, whfrag, hbuf, (float*)d_out);
}

// Round 12
// 1638.002 us; speedup vs baseline: 1.9331x; 1.0700x over previous
//
#include <hip/hip_runtime.h>
#include <hip/hip_bf16.h>

// LSTM: B=64, T=512, I=512, H=512. Output = final h [64,512] fp32.
//
// Round 12 = round 11 + tail-shortening (bit-exact):
//   (1) bias+x folded into MFMA C-init (acc0), computed BEFORE the poll
//       from the previous step's xact prefetch -> post-MFMA adds gone.
//   (2) Scalar butterfly: exchange RAW pre-activations with 3 shfl_xor
//       (masks 4,8,12): sender (gate g) sends own[g^k]; receiver lane
//       (gate g) receives gate (g^k)'s value for ITS OWN row. Receiver
//       applies fixed-role activations (f,i,o = sigmoid; C = tanh),
//       keeps SCALAR c (was 4x-redundant f32x4), one tanh, publish.
//       12 swizzles + 16 vector selects -> 3 swizzles + ~12 cndmasks.
//   Decision recorded: intra-XCD L2 sync transport abandoned — rounds 8/9
//   (placement consensus-verified, still wrong) imply agent coherence is
//   only encodable at the MALL on gfx950.
//
//   Carried (r11-proven): slot-per-producer-wave coalesced transport
//   hbuf[par][cl][(w*4+v)*64+lane] tagged (step<<16)|bf16(h); consumer
//   polls its 8KB K-quarter as 8 fully-coalesced dwordx4; tag-in-word =
//   poll IS the payload (1 MALL trip/step); slot->A-frag permutation via
//   LDS (verified); 4 clusters x 32 WGs x 16 batches; s=0 poll skip;
//   4-chain MFMA; xact = x@W_x precomputed; W_h register-resident;
//   single barrier/step, double-buffered alds; agent (sc0 sc1) transport.

#define T_STEPS 512
#define NBATCH  64
#define HID     512
#define NCL     4
#define WPC     32
#define CLB     16

typedef __attribute__((ext_vector_type(8))) short bf16x8;
typedef __attribute__((ext_vector_type(4))) float f32x4;
typedef __attribute__((ext_vector_type(4))) unsigned u32x4;
typedef __attribute__((ext_vector_type(2))) unsigned u32x2;

// ws layout (bytes)
#define WS_WHF  0                        // whfrag bf16, frag-order: 2MB
#define WS_WXT  (4u<<20)                 // wxT bf16 [2048][512]: 2MB
#define WS_HB   (8u<<20)                 // hbuf tagged u32 [2][4][8192]: 256KB
#define WS_XBF  (16u<<20)                // xbf bf16 [32768][512]: 32MB
#define WS_XACT (48u<<20)                // xact bf16 [512][64][2048]: 128MB
#define WS_NEED ((size_t)(48u<<20) + ((size_t)T_STEPS*NBATCH*2048*2))

__device__ __forceinline__ short f2bf(float f) {
    unsigned u = __float_as_uint(f);
    unsigned r = u + 0x7fffu + ((u >> 16) & 1u);   // RNE
    return (short)(r >> 16);
}

__global__ void prep_xbf(const float* __restrict__ x, short* __restrict__ xbf) {
    size_t i8 = ((size_t)blockIdx.x * 256 + threadIdx.x) * 8;   // 8192 blocks
    f32x4 lo = *(const f32x4*)(x + i8);
    f32x4 hi = *(const f32x4*)(x + i8 + 4);
    bf16x8 v;
    v[0]=f2bf(lo[0]); v[1]=f2bf(lo[1]); v[2]=f2bf(lo[2]); v[3]=f2bf(lo[3]);
    v[4]=f2bf(hi[0]); v[5]=f2bf(hi[1]); v[6]=f2bf(hi[2]); v[7]=f2bf(hi[3]);
    *(bf16x8*)(xbf + i8) = v;
}

// wxT[n][k] = W_g[k][h], n = g*512+h, k in [0,512)  (x-part rows of W)
__global__ void prep_wx(const float* __restrict__ Wf, const float* __restrict__ Wi,
                        const float* __restrict__ Wo, const float* __restrict__ Wc,
                        short* __restrict__ wxT) {
    int gid = blockIdx.x * 256 + threadIdx.x;      // 512 blocks
    int n = gid >> 6, k0 = (gid & 63) * 8;
    int g = n >> 9, h = n & 511;
    const float* Wg = (g == 0) ? Wf : (g == 1) ? Wi : (g == 2) ? Wo : Wc;
    bf16x8 v;
#pragma unroll
    for (int e = 0; e < 8; ++e) v[e] = f2bf(Wg[(k0 + e) * 512 + h]);
    *(bf16x8*)(wxT + (size_t)n * 512 + k0) = v;
}

// whfrag, frag-order, GATE-MAJOR cols: B-tile col (l&15) = gate*4+hcl,
// hcol = 16w + 4v + hcl; value = W_gate[512 + kk*32 + (l>>4)*8 + e][hcol]
__global__ void prep_wh(const float* __restrict__ Wf, const float* __restrict__ Wi,
                        const float* __restrict__ Wo, const float* __restrict__ Wc,
                        short* __restrict__ whfrag) {
    int gid = blockIdx.x * 256 + threadIdx.x;      // 512 blocks: 32w*4v*16kk*64l
    int l = gid & 63, kk = (gid >> 6) & 15, v = (gid >> 10) & 3, w = gid >> 12;
    int c16 = l & 15, gate = c16 >> 2, hcl = c16 & 3;
    int hcol = 16 * w + 4 * v + hcl;
    const float* Wg = (gate == 0) ? Wf : (gate == 1) ? Wi : (gate == 2) ? Wo : Wc;
    int krow = 512 + kk * 32 + (l >> 4) * 8;
    bf16x8 vv;
#pragma unroll
    for (int e = 0; e < 8; ++e) vv[e] = f2bf(Wg[(krow + e) * 512 + hcol]);
    *(bf16x8*)(whfrag + (size_t)gid * 8) = vv;
}

// xact GEMM: [M=32768,K=512] x [K=512,N=2048] -> xact[t][b][n] bf16
__launch_bounds__(256, 1)
__global__ void xgemm(const short* __restrict__ xbf, const short* __restrict__ wxT,
                      short* __restrict__ xact) {
    const int l  = threadIdx.x & 63;
    const int wv = threadIdx.x >> 6;
    const int m0 = blockIdx.y * 128 + (wv >> 1) * 64;
    const int n0 = blockIdx.x * 128 + (wv & 1) * 64;

    f32x4 acc[4][4] = {};
    const short* ap = xbf + (size_t)(m0 + (l & 15)) * 512 + (l >> 4) * 8;
    const short* bp = wxT + (size_t)(n0 + (l & 15)) * 512 + (l >> 4) * 8;

    for (int kk = 0; kk < 16; ++kk) {
        bf16x8 a[4], b[4];
#pragma unroll
        for (int r = 0; r < 4; ++r) a[r] = *(const bf16x8*)(ap + r * 8192 + kk * 32);
#pragma unroll
        for (int q = 0; q < 4; ++q) b[q] = *(const bf16x8*)(bp + q * 8192 + kk * 32);
#pragma unroll
        for (int r = 0; r < 4; ++r)
#pragma unroll
            for (int q = 0; q < 4; ++q)
                acc[r][q] = __builtin_amdgcn_mfma_f32_16x16x32_bf16(a[r], b[q], acc[r][q], 0, 0, 0);
    }
#pragma unroll
    for (int r = 0; r < 4; ++r)
#pragma unroll
        for (int q = 0; q < 4; ++q)
#pragma unroll
            for (int j = 0; j < 4; ++j) {
                int m = m0 + r * 16 + (l >> 4) * 4 + j;
                int b_ = m >> 9, t = m & 511;
                int n = n0 + q * 16 + (l & 15);
                xact[((size_t)t * 64 + b_) * 2048 + n] = f2bf(acc[r][q][j]);
            }
}

__device__ __forceinline__ float vsel(f32x4 v, int idx) {
    // runtime-per-lane index -> cndmask chain (rule #20: no dynamic array idx)
    float lo = (idx & 1) ? v[1] : v[0];
    float hi = (idx & 1) ? v[3] : v[2];
    return (idx & 2) ? hi : lo;
}
__device__ __forceinline__ float sigm_f(float x) {
    float e = __builtin_amdgcn_exp2f(-1.442695041f * x);
    return __builtin_amdgcn_rcpf(1.f + e);
}
__device__ __forceinline__ float tanh_f(float x) {
    float e = __builtin_amdgcn_exp2f(-2.885390082f * x);
    return __builtin_fmaf(2.f, __builtin_amdgcn_rcpf(1.f + e), -1.f);
}

// 8 x 16B coalesced poll loads (two bases: 13-bit signed offset caps at 4095)
#define POLL8X                                                                \
    asm volatile(                                                             \
        "global_load_dwordx4 %[t0], %[p], off sc0 sc1\n\t"                    \
        "global_load_dwordx4 %[t1], %[p], off offset:1024 sc0 sc1\n\t"        \
        "global_load_dwordx4 %[t2], %[p], off offset:2048 sc0 sc1\n\t"        \
        "global_load_dwordx4 %[t3], %[p], off offset:3072 sc0 sc1\n\t"        \
        "global_load_dwordx4 %[t4], %[q], off sc0 sc1\n\t"                    \
        "global_load_dwordx4 %[t5], %[q], off offset:1024 sc0 sc1\n\t"        \
        "global_load_dwordx4 %[t6], %[q], off offset:2048 sc0 sc1\n\t"        \
        "global_load_dwordx4 %[t7], %[q], off offset:3072 sc0 sc1\n\t"        \
        "s_waitcnt vmcnt(0)"                                                  \
        : [t0]"=v"(t0), [t1]"=v"(t1), [t2]"=v"(t2), [t3]"=v"(t3),             \
          [t4]"=v"(t4), [t5]"=v"(t5), [t6]"=v"(t6), [t7]"=v"(t7)              \
        : [p]"v"(hp), [q]"v"(hq) : "memory")

// ---- recurrence -------------------------------------------------------------
__launch_bounds__(256, 1)
__global__ void lstm_rec(const short* __restrict__ xact,
                         const float* __restrict__ bfp, const float* __restrict__ bip,
                         const float* __restrict__ bop, const float* __restrict__ bcp,
                         const short* __restrict__ whfrag,
                         unsigned* __restrict__ hbuf,     // [2][4][8192] tagged
                         float* __restrict__ out)         // [64][512] fp32
{
    const int tid = threadIdx.x;
    const int v   = tid >> 6;           // wave = hcol sub-slice / K-quarter
    const int l   = tid & 63;
    const int bid = blockIdx.x;
    const int cl  = bid & (NCL - 1);    // cluster (16 batches)
    const int w   = bid >> 2;           // 0..31: 16 hcols of 512
    const int batch0 = cl * CLB;

    // ---- W_h fragments: 16 x bf16x8, register-resident ----
    bf16x8 wfr[16];
    {
        const short* wp = whfrag + (((size_t)(w * 4 + v) * 16) * 64 + l) * 8;
#pragma unroll
        for (int kk = 0; kk < 16; ++kk)
            wfr[kk] = *(const bf16x8*)(wp + (size_t)kk * 512);
#pragma unroll
        for (int kk = 0; kk < 16; ++kk)
            asm volatile("" : "+v"(wfr[kk]));
    }

    const int g    = (l >> 2) & 3;              // lane's gate
    const int hcol = 16 * w + 4 * v + (l & 3);  // lane's h column
    const int kg   = l >> 4;
    const float* bp2 = (g == 0) ? bfp : (g == 1) ? bip : (g == 2) ? bop : bcp;
    const float bias = bp2[hcol];

    __shared__ short alds[2][16][64][8];   // A-frags, double-buffered (32KB)

    const int rowD0 = batch0 + kg * 4;      // D-frag row base (+j)
    const unsigned short* xa = (const unsigned short*)xact;
    size_t xoff[4];
#pragma unroll
    for (int j = 0; j < 4; ++j)
        xoff[j] = (size_t)(rowD0 + j) * 2048 + (size_t)g * 512 + hcol;

    // slot->A-frag permutation constants (r11-verified):
    const int rowT = l & 15;
    const int qb   = l >> 5;
    const int e0s  = 4 * ((l >> 4) & 1);

    float c = 0.f;                       // SCALAR cell state (row rowD0+g)
    bool dead = false;

    // xact for s=0 (plain compiler-tracked loads)
    unsigned short xw[4], xwn[4];
#pragma unroll
    for (int j = 0; j < 4; ++j) xw[j] = xa[xoff[j]];

    for (int s = 0; s < T_STEPS; ++s) {
        // ---- MFMA C-init = bias + x (computed in dead poll time) ----
        f32x4 init;
#pragma unroll
        for (int j = 0; j < 4; ++j)
            init[j] = bias + __uint_as_float((unsigned)xw[j] << 16);

        // ---- poll K-quarter v of h_s: 8KB slot region, fully coalesced ----
        u32x4 t0 = {}, t1 = {}, t2 = {}, t3 = {}, t4 = {}, t5 = {}, t6 = {}, t7 = {};
        if (s) {
            const char* hp = (const char*)(hbuf + (size_t)(s & 1) * (NCL * 8192)
                                           + cl * 8192 + v * 2048) + l * 16;
            const char* hq = hp + 4096;
            const unsigned tagw = (unsigned)s << 16;
            int spin = 0;
            while (true) {
                POLL8X;
                unsigned m = 0;
#pragma unroll
                for (int e = 0; e < 4; ++e) {
                    m |= (t0[e] ^ tagw) & 0xFFFF0000u; m |= (t1[e] ^ tagw) & 0xFFFF0000u;
                    m |= (t2[e] ^ tagw) & 0xFFFF0000u; m |= (t3[e] ^ tagw) & 0xFFFF0000u;
                    m |= (t4[e] ^ tagw) & 0xFFFF0000u; m |= (t5[e] ^ tagw) & 0xFFFF0000u;
                    m |= (t6[e] ^ tagw) & 0xFFFF0000u; m |= (t7[e] ^ tagw) & 0xFFFF0000u;
                }
                if (__all(m == 0) || dead) break;
                if (++spin > (1 << 17)) dead = true;
                else if (spin > 16) __builtin_amdgcn_s_sleep(1);
            }
        }

        // ---- xact prefetch for s+1 (plain loads, compiler-tracked) ----
        if (s + 1 < T_STEPS) {
#pragma unroll
            for (int j = 0; j < 4; ++j)
                xwn[j] = xa[(size_t)(s + 1) * 131072 + xoff[j]];
        }

        // ---- slot->A-frag permutation: tag-strip + 8 x ds_write_b64 ----
        const int par = s & 1;
#define WRCHUNK(mm, tv)                                                        \
        {                                                                      \
            u32x2 d;                                                           \
            d[0] = __builtin_amdgcn_perm(tv[1], tv[0], 0x05040100u);           \
            d[1] = __builtin_amdgcn_perm(tv[3], tv[2], 0x05040100u);           \
            const int Qw = (2 * (mm) + qb) & 3;                                \
            *(u32x2*)&alds[par][4 * v + ((mm) >> 1)][(Qw << 4) | rowT][e0s] = d; \
        }
        WRCHUNK(0, t0) WRCHUNK(1, t1) WRCHUNK(2, t2) WRCHUNK(3, t3)
        WRCHUNK(4, t4) WRCHUNK(5, t5) WRCHUNK(6, t6) WRCHUNK(7, t7)
#undef WRCHUNK
        __syncthreads();   // single barrier per step (dbuf makes it safe)

        // ---- 16 MFMA over K=512, 4 independent chains (acc0 = bias+x) ----
        f32x4 acc0 = init;
        f32x4 acc1 = {0.f,0.f,0.f,0.f};
        f32x4 acc2 = {0.f,0.f,0.f,0.f}, acc3 = {0.f,0.f,0.f,0.f};
#pragma unroll
        for (int kk = 0; kk < 16; kk += 4) {
            bf16x8 a0 = *(const bf16x8*)&alds[par][kk][l][0];
            bf16x8 a1 = *(const bf16x8*)&alds[par][kk + 1][l][0];
            bf16x8 a2 = *(const bf16x8*)&alds[par][kk + 2][l][0];
            bf16x8 a3 = *(const bf16x8*)&alds[par][kk + 3][l][0];
            acc0 = __builtin_amdgcn_mfma_f32_16x16x32_bf16(a0, wfr[kk],     acc0, 0, 0, 0);
            acc1 = __builtin_amdgcn_mfma_f32_16x16x32_bf16(a1, wfr[kk + 1], acc1, 0, 0, 0);
            acc2 = __builtin_amdgcn_mfma_f32_16x16x32_bf16(a2, wfr[kk + 2], acc2, 0, 0, 0);
            acc3 = __builtin_amdgcn_mfma_f32_16x16x32_bf16(a3, wfr[kk + 3], acc3, 0, 0, 0);
        }
        f32x4 pre = (acc0 + acc1) + (acc2 + acc3);   // RAW gate pre-activations

#pragma unroll
        for (int j = 0; j < 4; ++j) xw[j] = xwn[j];

        // ---- scalar butterfly: 3 swizzles of RAW values ----
        // sender (gate g) sends own pre[g^k]; receiver gets gate (g^k)'s
        // value for ITS row (rowD0+g). r_k = value from gate (g^k).
        float s0 = vsel(pre, g);
        float s1 = vsel(pre, g ^ 1);
        float s2 = vsel(pre, g ^ 2);
        float s3 = vsel(pre, g ^ 3);
        float r1 = __shfl_xor(s1, 4);
        float r2 = __shfl_xor(s2, 8);
        float r3 = __shfl_xor(s3, 12);
        // gate j's raw value = r_{g^j} (r_0 == s0)
        float rf = (g == 0) ? s0 : (g == 1) ? r1 : (g == 2) ? r2 : r3;
        float ri = (g == 1) ? s0 : (g == 0) ? r1 : (g == 3) ? r2 : r3;
        float ro = (g == 2) ? s0 : (g == 3) ? r1 : (g == 0) ? r2 : r3;
        float rC = (g == 3) ? s0 : (g == 2) ? r1 : (g == 1) ? r2 : r3;

        // ---- fixed-role activations + scalar c,h (this lane's row) ----
        float fv = sigm_f(rf);
        float iv = sigm_f(ri);
        float ov = sigm_f(ro);
        float Cv = tanh_f(rC);
        c = __builtin_fmaf(fv, c, iv * Cv);
        float h = ov * tanh_f(c);

        // ---- publish: wave-contiguous slot store (4 full lines/wave) ----
        if (s == T_STEPS - 1) {
            out[(rowD0 + g) * HID + hcol] = h;
        } else {
            unsigned* hd = hbuf + (size_t)((s + 1) & 1) * (NCL * 8192)
                         + cl * 8192 + (w * 4 + v) * 64 + l;
            unsigned  hv = ((unsigned)(s + 1) << 16) |
                           (unsigned)(unsigned short)f2bf(h);
            asm volatile("global_store_dword %0, %1, off sc0 sc1"
                         :: "v"(hd), "v"(hv) : "memory");
        }
    }
}

extern "C" void kernel_launch(void* const* d_in, const int* in_sizes, int n_in,
                              void* d_out, int out_size, void* d_ws, size_t ws_size,
                              hipStream_t stream) {
    const float* x  = (const float*)d_in[0];
    const float* Wf = (const float*)d_in[1];
    const float* bf = (const float*)d_in[2];
    const float* Wi = (const float*)d_in[3];
    const float* bi = (const float*)d_in[4];
    const float* Wo = (const float*)d_in[5];
    const float* bo = (const float*)d_in[6];
    const float* Wc = (const float*)d_in[7];
    const float* bc = (const float*)d_in[8];

    if (ws_size < WS_NEED) return;   // loud failure: out stays poison

    char*     ws     = (char*)d_ws;
    short*    whfrag = (short*)(ws + WS_WHF);
    short*    wxT    = (short*)(ws + WS_WXT);
    unsigned* hbuf   = (unsigned*)(ws + WS_HB);
    short*    xbf    = (short*)(ws + WS_XBF);
    short*    xact   = (short*)(ws + WS_XACT);

    prep_xbf <<<dim3(8192), dim3(256), 0, stream>>>(x, xbf);
    prep_wx  <<<dim3(512),  dim3(256), 0, stream>>>(Wf, Wi, Wo, Wc, wxT);
    prep_wh  <<<dim3(512),  dim3(256), 0, stream>>>(Wf, Wi, Wo, Wc, whfrag);
    xgemm    <<<dim3(16, 256), dim3(256), 0, stream>>>(xbf, wxT, xact);
    lstm_rec <<<dim3(NCL * WPC), dim3(256), 0, stream>>>(
        xact, bf, bi, bo, bc, whfrag, hbuf, (float*)d_out);
}

// Round 14
// 1390.994 us; speedup vs baseline: 2.2764x; 1.1776x over previous
//
#include <hip/hip_runtime.h>
#include <hip/hip_bf16.h>

// LSTM: B=64, T=512, I=512, H=512. Output = final h [64,512] fp32.
//
// Round 14 = round 12 + SAFE same-register pipelined polling.
//   Round 13 crashed: ping-pong left loads in flight targeting registers
//   the allocator had freed (and the u->t copy overwrote in-flight dests).
//   This version reissues each poll round INTO THE SAME REGISTERS ("+v"
//   constraints -> no copies, same vregs) and waits with counted
//   s_waitcnt vmcnt(8) (oldest-first retirement, m135) so the previous
//   round is landed while the next is mid-flight: poll period ~RT/2.
//   Why same-register clobber is benign: tag-in-word self-validates each
//   32-bit word (any round-k/round-k+1 mix with all tags==s is correct),
//   and within an epoch each address is written once (monotone) so a
//   newer load of the same address returns identical bits.
//   Liveness discipline: t0..t7 are function-scope with a loop-carried
//   "+v" chain; the poll-start vmcnt(0) drain (already needed, zero extra
//   cost) and a final post-loop drain carry "+v" anchors so the allocator
//   can NEVER reuse the registers while a load is in flight.
//
//   Carried (proven r11/r12/r13): slot-per-producer-wave coalesced
//   transport hbuf[par][cl][(w*4+v)*64+lane] tagged (step<<16)|bf16(h);
//   poll IS the payload (1 MALL trip/step); slot->A-frag LDS permutation;
//   4 clusters x 32 WGs x 16 batches; bias+x folded into MFMA C-init;
//   scalar butterfly (3 shfl_xor, scalar c); 4-chain MFMA; W_h register-
//   resident; agent (sc0 sc1) transport; single barrier/step, dbuf alds;
//   alds parity-0 prezeroed -> s=0 skips poll+WRCHUNK.

#define T_STEPS 512
#define NBATCH  64
#define HID     512
#define NCL     4
#define WPC     32
#define CLB     16

typedef __attribute__((ext_vector_type(8))) short bf16x8;
typedef __attribute__((ext_vector_type(4))) float f32x4;
typedef __attribute__((ext_vector_type(4))) unsigned u32x4;
typedef __attribute__((ext_vector_type(2))) unsigned u32x2;

// ws layout (bytes)
#define WS_WHF  0                        // whfrag bf16, frag-order: 2MB
#define WS_WXT  (4u<<20)                 // wxT bf16 [2048][512]: 2MB
#define WS_HB   (8u<<20)                 // hbuf tagged u32 [2][4][8192]: 256KB
#define WS_XBF  (16u<<20)                // xbf bf16 [32768][512]: 32MB
#define WS_XACT (48u<<20)                // xact bf16 [512][64][2048]: 128MB
#define WS_NEED ((size_t)(48u<<20) + ((size_t)T_STEPS*NBATCH*2048*2))

__device__ __forceinline__ short f2bf(float f) {
    unsigned u = __float_as_uint(f);
    unsigned r = u + 0x7fffu + ((u >> 16) & 1u);   // RNE
    return (short)(r >> 16);
}

__global__ void prep_xbf(const float* __restrict__ x, short* __restrict__ xbf) {
    size_t i8 = ((size_t)blockIdx.x * 256 + threadIdx.x) * 8;   // 8192 blocks
    f32x4 lo = *(const f32x4*)(x + i8);
    f32x4 hi = *(const f32x4*)(x + i8 + 4);
    bf16x8 v;
    v[0]=f2bf(lo[0]); v[1]=f2bf(lo[1]); v[2]=f2bf(lo[2]); v[3]=f2bf(lo[3]);
    v[4]=f2bf(hi[0]); v[5]=f2bf(hi[1]); v[6]=f2bf(hi[2]); v[7]=f2bf(hi[3]);
    *(bf16x8*)(xbf + i8) = v;
}

// wxT[n][k] = W_g[k][h], n = g*512+h, k in [0,512)  (x-part rows of W)
__global__ void prep_wx(const float* __restrict__ Wf, const float* __restrict__ Wi,
                        const float* __restrict__ Wo, const float* __restrict__ Wc,
                        short* __restrict__ wxT) {
    int gid = blockIdx.x * 256 + threadIdx.x;      // 512 blocks
    int n = gid >> 6, k0 = (gid & 63) * 8;
    int g = n >> 9, h = n & 511;
    const float* Wg = (g == 0) ? Wf : (g == 1) ? Wi : (g == 2) ? Wo : Wc;
    bf16x8 v;
#pragma unroll
    for (int e = 0; e < 8; ++e) v[e] = f2bf(Wg[(k0 + e) * 512 + h]);
    *(bf16x8*)(wxT + (size_t)n * 512 + k0) = v;
}

// whfrag, frag-order, GATE-MAJOR cols: B-tile col (l&15) = gate*4+hcl,
// hcol = 16w + 4v + hcl; value = W_gate[512 + kk*32 + (l>>4)*8 + e][hcol]
__global__ void prep_wh(const float* __restrict__ Wf, const float* __restrict__ Wi,
                        const float* __restrict__ Wo, const float* __restrict__ Wc,
                        short* __restrict__ whfrag) {
    int gid = blockIdx.x * 256 + threadIdx.x;      // 512 blocks: 32w*4v*16kk*64l
    int l = gid & 63, kk = (gid >> 6) & 15, v = (gid >> 10) & 3, w = gid >> 12;
    int c16 = l & 15, gate = c16 >> 2, hcl = c16 & 3;
    int hcol = 16 * w + 4 * v + hcl;
    const float* Wg = (gate == 0) ? Wf : (gate == 1) ? Wi : (gate == 2) ? Wo : Wc;
    int krow = 512 + kk * 32 + (l >> 4) * 8;
    bf16x8 vv;
#pragma unroll
    for (int e = 0; e < 8; ++e) vv[e] = f2bf(Wg[(krow + e) * 512 + hcol]);
    *(bf16x8*)(whfrag + (size_t)gid * 8) = vv;
}

// xact GEMM: [M=32768,K=512] x [K=512,N=2048] -> xact[t][b][n] bf16
__launch_bounds__(256, 1)
__global__ void xgemm(const short* __restrict__ xbf, const short* __restrict__ wxT,
                      short* __restrict__ xact) {
    const int l  = threadIdx.x & 63;
    const int wv = threadIdx.x >> 6;
    const int m0 = blockIdx.y * 128 + (wv >> 1) * 64;
    const int n0 = blockIdx.x * 128 + (wv & 1) * 64;

    f32x4 acc[4][4] = {};
    const short* ap = xbf + (size_t)(m0 + (l & 15)) * 512 + (l >> 4) * 8;
    const short* bp = wxT + (size_t)(n0 + (l & 15)) * 512 + (l >> 4) * 8;

    for (int kk = 0; kk < 16; ++kk) {
        bf16x8 a[4], b[4];
#pragma unroll
        for (int r = 0; r < 4; ++r) a[r] = *(const bf16x8*)(ap + r * 8192 + kk * 32);
#pragma unroll
        for (int q = 0; q < 4; ++q) b[q] = *(const bf16x8*)(bp + q * 8192 + kk * 32);
#pragma unroll
        for (int r = 0; r < 4; ++r)
#pragma unroll
            for (int q = 0; q < 4; ++q)
                acc[r][q] = __builtin_amdgcn_mfma_f32_16x16x32_bf16(a[r], b[q], acc[r][q], 0, 0, 0);
    }
#pragma unroll
    for (int r = 0; r < 4; ++r)
#pragma unroll
        for (int q = 0; q < 4; ++q)
#pragma unroll
            for (int j = 0; j < 4; ++j) {
                int m = m0 + r * 16 + (l >> 4) * 4 + j;
                int b_ = m >> 9, t = m & 511;
                int n = n0 + q * 16 + (l & 15);
                xact[((size_t)t * 64 + b_) * 2048 + n] = f2bf(acc[r][q][j]);
            }
}

__device__ __forceinline__ float vsel(f32x4 v, int idx) {
    float lo = (idx & 1) ? v[1] : v[0];
    float hi = (idx & 1) ? v[3] : v[2];
    return (idx & 2) ? hi : lo;
}
__device__ __forceinline__ float sigm_f(float x) {
    float e = __builtin_amdgcn_exp2f(-1.442695041f * x);
    return __builtin_amdgcn_rcpf(1.f + e);
}
__device__ __forceinline__ float tanh_f(float x) {
    float e = __builtin_amdgcn_exp2f(-2.885390082f * x);
    return __builtin_fmaf(2.f, __builtin_amdgcn_rcpf(1.f + e), -1.f);
}

// issue 8 coalesced 16B poll loads into the SAME registers ("+v"), no wait
#define PISSUE                                                                \
    asm volatile(                                                             \
        "global_load_dwordx4 %[r0], %[p], off sc0 sc1\n\t"                    \
        "global_load_dwordx4 %[r1], %[p], off offset:1024 sc0 sc1\n\t"        \
        "global_load_dwordx4 %[r2], %[p], off offset:2048 sc0 sc1\n\t"        \
        "global_load_dwordx4 %[r3], %[p], off offset:3072 sc0 sc1\n\t"        \
        "global_load_dwordx4 %[r4], %[q], off sc0 sc1\n\t"                    \
        "global_load_dwordx4 %[r5], %[q], off offset:1024 sc0 sc1\n\t"        \
        "global_load_dwordx4 %[r6], %[q], off offset:2048 sc0 sc1\n\t"        \
        "global_load_dwordx4 %[r7], %[q], off offset:3072 sc0 sc1"            \
        : [r0]"+v"(t0), [r1]"+v"(t1), [r2]"+v"(t2), [r3]"+v"(t3),             \
          [r4]"+v"(t4), [r5]"+v"(t5), [r6]"+v"(t6), [r7]"+v"(t7)              \
        : [p]"v"(hp), [q]"v"(hq) : "memory")

// wait until <=8 outstanding (oldest round landed); values data-ordered
#define PWAIT8                                                                \
    asm volatile("s_waitcnt vmcnt(8)"                                         \
        : [r0]"+v"(t0), [r1]"+v"(t1), [r2]"+v"(t2), [r3]"+v"(t3),             \
          [r4]"+v"(t4), [r5]"+v"(t5), [r6]"+v"(t6), [r7]"+v"(t7)              \
        :: "memory");                                                         \
    __builtin_amdgcn_sched_barrier(0)

// full drain WITH liveness anchors (allocator cannot reuse t while in flight)
#define PDRAIN                                                                \
    asm volatile("s_waitcnt vmcnt(0)"                                         \
        : [r0]"+v"(t0), [r1]"+v"(t1), [r2]"+v"(t2), [r3]"+v"(t3),             \
          [r4]"+v"(t4), [r5]"+v"(t5), [r6]"+v"(t6), [r7]"+v"(t7)              \
        :: "memory")

// ---- recurrence -------------------------------------------------------------
__launch_bounds__(256, 1)
__global__ void lstm_rec(const short* __restrict__ xact,
                         const float* __restrict__ bfp, const float* __restrict__ bip,
                         const float* __restrict__ bop, const float* __restrict__ bcp,
                         const short* __restrict__ whfrag,
                         unsigned* __restrict__ hbuf,     // [2][4][8192] tagged
                         float* __restrict__ out)         // [64][512] fp32
{
    const int tid = threadIdx.x;
    const int v   = tid >> 6;           // wave = hcol sub-slice / K-quarter
    const int l   = tid & 63;
    const int bid = blockIdx.x;
    const int cl  = bid & (NCL - 1);    // cluster (16 batches)
    const int w   = bid >> 2;           // 0..31: 16 hcols of 512
    const int batch0 = cl * CLB;

    // ---- W_h fragments: 16 x bf16x8, register-resident ----
    bf16x8 wfr[16];
    {
        const short* wp = whfrag + (((size_t)(w * 4 + v) * 16) * 64 + l) * 8;
#pragma unroll
        for (int kk = 0; kk < 16; ++kk)
            wfr[kk] = *(const bf16x8*)(wp + (size_t)kk * 512);
#pragma unroll
        for (int kk = 0; kk < 16; ++kk)
            asm volatile("" : "+v"(wfr[kk]));
    }

    const int g    = (l >> 2) & 3;              // lane's gate
    const int hcol = 16 * w + 4 * v + (l & 3);  // lane's h column
    const int kg   = l >> 4;
    const float* bp2 = (g == 0) ? bfp : (g == 1) ? bip : (g == 2) ? bop : bcp;
    const float bias = bp2[hcol];

    __shared__ short alds[2][16][64][8];   // A-frags, double-buffered (32KB)

    // zero parity-0 buffer once (h0 == 0): s=0 skips poll AND WRCHUNK
    {
        short* z = &alds[0][0][0][0] + tid * 32;   // 256 thr x 64B = 16KB
#pragma unroll
        for (int q = 0; q < 4; ++q)
            *(u32x4*)(z + q * 8) = (u32x4){0u, 0u, 0u, 0u};
    }

    const int rowD0 = batch0 + kg * 4;      // D-frag row base (+j)
    const unsigned short* xa = (const unsigned short*)xact;
    size_t xoff[4];
#pragma unroll
    for (int j = 0; j < 4; ++j)
        xoff[j] = (size_t)(rowD0 + j) * 2048 + (size_t)g * 512 + hcol;

    // slot->A-frag permutation constants (r11-verified):
    const int rowT = l & 15;
    const int qb   = l >> 5;
    const int e0s  = 4 * ((l >> 4) & 1);

    float c = 0.f;                       // SCALAR cell state (row rowD0+g)

    // poll registers: FUNCTION SCOPE, loop-carried "+v" chain pins the vregs
    u32x4 t0 = {}, t1 = {}, t2 = {}, t3 = {}, t4 = {}, t5 = {}, t6 = {}, t7 = {};

    // xact for s=0 (plain compiler-tracked loads)
    unsigned short xw[4], xwn[4];
#pragma unroll
    for (int j = 0; j < 4; ++j) xw[j] = xa[xoff[j]];

    for (int s = 0; s < T_STEPS; ++s) {
        // ---- MFMA C-init = bias + x (dead poll time) ----
        f32x4 init;
#pragma unroll
        for (int j = 0; j < 4; ++j)
            init[j] = bias + __uint_as_float((unsigned)xw[j] << 16);

        // ---- pipelined same-register poll of K-quarter v of h_s ----
        if (s) {
            const char* hp = (const char*)(hbuf + (size_t)(s & 1) * (NCL * 8192)
                                           + cl * 8192 + v * 2048) + l * 16;
            const char* hq = hp + 4096;
            const unsigned tagw = (unsigned)s << 16;
            PDRAIN;            // retire stragglers from last step's poll
            PISSUE;            // round 1
            int spin = 0;
            while (true) {
                PISSUE;        // round k+1 into the same regs (benign: tags)
                PWAIT8;        // round k landed (oldest-first retirement)
                unsigned m = 0;
#pragma unroll
                for (int e = 0; e < 4; ++e) {
                    m |= (t0[e] ^ tagw) & 0xFFFF0000u; m |= (t1[e] ^ tagw) & 0xFFFF0000u;
                    m |= (t2[e] ^ tagw) & 0xFFFF0000u; m |= (t3[e] ^ tagw) & 0xFFFF0000u;
                    m |= (t4[e] ^ tagw) & 0xFFFF0000u; m |= (t5[e] ^ tagw) & 0xFFFF0000u;
                    m |= (t6[e] ^ tagw) & 0xFFFF0000u; m |= (t7[e] ^ tagw) & 0xFFFF0000u;
                }
                if (__all(m == 0)) break;
                if (++spin > (1 << 17)) break;             // no-hang bailout
                if (spin > 64) __builtin_amdgcn_s_sleep(1);
            }
            // exit: <=8 loads in flight into t (same epoch addresses ->
            // identical bits when they land; liveness held to next PDRAIN)
        }

        // ---- xact prefetch for s+1 (plain loads, compiler-tracked) ----
        if (s + 1 < T_STEPS) {
#pragma unroll
            for (int j = 0; j < 4; ++j)
                xwn[j] = xa[(size_t)(s + 1) * 131072 + xoff[j]];
        }

        // ---- slot->A-frag permutation: tag-strip + 8 x ds_write_b64 ----
        const int par = s & 1;
        if (s) {
#define WRCHUNK(mm, tv)                                                        \
            {                                                                  \
                u32x2 d;                                                       \
                d[0] = __builtin_amdgcn_perm(tv[1], tv[0], 0x05040100u);       \
                d[1] = __builtin_amdgcn_perm(tv[3], tv[2], 0x05040100u);       \
                const int Qw = (2 * (mm) + qb) & 3;                            \
                *(u32x2*)&alds[par][4 * v + ((mm) >> 1)][(Qw << 4) | rowT][e0s] = d; \
            }
            WRCHUNK(0, t0) WRCHUNK(1, t1) WRCHUNK(2, t2) WRCHUNK(3, t3)
            WRCHUNK(4, t4) WRCHUNK(5, t5) WRCHUNK(6, t6) WRCHUNK(7, t7)
#undef WRCHUNK
        }
        __syncthreads();   // single barrier per step (dbuf makes it safe)

        // ---- 16 MFMA over K=512, 4 independent chains (acc0 = bias+x) ----
        f32x4 acc0 = init;
        f32x4 acc1 = {0.f,0.f,0.f,0.f};
        f32x4 acc2 = {0.f,0.f,0.f,0.f}, acc3 = {0.f,0.f,0.f,0.f};
#pragma unroll
        for (int kk = 0; kk < 16; kk += 4) {
            bf16x8 a0 = *(const bf16x8*)&alds[par][kk][l][0];
            bf16x8 a1 = *(const bf16x8*)&alds[par][kk + 1][l][0];
            bf16x8 a2 = *(const bf16x8*)&alds[par][kk + 2][l][0];
            bf16x8 a3 = *(const bf16x8*)&alds[par][kk + 3][l][0];
            acc0 = __builtin_amdgcn_mfma_f32_16x16x32_bf16(a0, wfr[kk],     acc0, 0, 0, 0);
            acc1 = __builtin_amdgcn_mfma_f32_16x16x32_bf16(a1, wfr[kk + 1], acc1, 0, 0, 0);
            acc2 = __builtin_amdgcn_mfma_f32_16x16x32_bf16(a2, wfr[kk + 2], acc2, 0, 0, 0);
            acc3 = __builtin_amdgcn_mfma_f32_16x16x32_bf16(a3, wfr[kk + 3], acc3, 0, 0, 0);
        }
        f32x4 pre = (acc0 + acc1) + (acc2 + acc3);   // RAW gate pre-activations

#pragma unroll
        for (int j = 0; j < 4; ++j) xw[j] = xwn[j];

        // ---- scalar butterfly: 3 swizzles of RAW values ----
        float s0 = vsel(pre, g);
        float s1 = vsel(pre, g ^ 1);
        float s2 = vsel(pre, g ^ 2);
        float s3 = vsel(pre, g ^ 3);
        float r1 = __shfl_xor(s1, 4);
        float r2 = __shfl_xor(s2, 8);
        float r3 = __shfl_xor(s3, 12);
        float rf = (g == 0) ? s0 : (g == 1) ? r1 : (g == 2) ? r2 : r3;
        float ri = (g == 1) ? s0 : (g == 0) ? r1 : (g == 3) ? r2 : r3;
        float ro = (g == 2) ? s0 : (g == 3) ? r1 : (g == 0) ? r2 : r3;
        float rC = (g == 3) ? s0 : (g == 2) ? r1 : (g == 1) ? r2 : r3;

        // ---- fixed-role activations + scalar c,h (this lane's row) ----
        float fv = sigm_f(rf);
        float iv = sigm_f(ri);
        float ov = sigm_f(ro);
        float Cv = tanh_f(rC);
        c = __builtin_fmaf(fv, c, iv * Cv);
        float h = ov * tanh_f(c);

        // ---- publish: wave-contiguous slot store (4 full lines/wave) ----
        if (s == T_STEPS - 1) {
            out[(rowD0 + g) * HID + hcol] = h;
        } else {
            unsigned* hd = hbuf + (size_t)((s + 1) & 1) * (NCL * 8192)
                         + cl * 8192 + (w * 4 + v) * 64 + l;
            unsigned  hv = ((unsigned)(s + 1) << 16) |
                           (unsigned)(unsigned short)f2bf(h);
            asm volatile("global_store_dword %0, %1, off sc0 sc1"
                         :: "v"(hd), "v"(hv) : "memory");
        }
    }

    // retire any in-flight poll loads before endpgm (registers anchored)
    PDRAIN;
}

extern "C" void kernel_launch(void* const* d_in, const int* in_sizes, int n_in,
                              void* d_out, int out_size, void* d_ws, size_t ws_size,
                              hipStream_t stream) {
    const float* x  = (const float*)d_in[0];
    const float* Wf = (const float*)d_in[1];
    const float* bf = (const float*)d_in[2];
    const float* Wi = (const float*)d_in[3];
    const float* bi = (const float*)d_in[4];
    const float* Wo = (const float*)d_in[5];
    const float* bo = (const float*)d_in[6];
    const float* Wc = (const float*)d_in[7];
    const float* bc = (const float*)d_in[8];

    if (ws_size < WS_NEED) return;   // loud failure: out stays poison

    char*     ws     = (char*)d_ws;
    short*    whfrag = (short*)(ws + WS_WHF);
    short*    wxT    = (short*)(ws + WS_WXT);
    unsigned* hbuf   = (unsigned*)(ws + WS_HB);
    short*    xbf    = (short*)(ws + WS_XBF);
    short*    xact   = (short*)(ws + WS_XACT);

    prep_xbf <<<dim3(8192), dim3(256), 0, stream>>>(x, xbf);
    prep_wx  <<<dim3(512),  dim3(256), 0, stream>>>(Wf, Wi, Wo, Wc, wxT);
    prep_wh  <<<dim3(512),  dim3(256), 0, stream>>>(Wf, Wi, Wo, Wc, whfrag);
    xgemm    <<<dim3(16, 256), dim3(256), 0, stream>>>(xbf, wxT, xact);
    lstm_rec <<<dim3(NCL * WPC), dim3(256), 0, stream>>>(
        xact, bf, bi, bo, bc, whfrag, hbuf, (float*)d_out);
}